// Round 5
// baseline (467.945 us; speedup 1.0000x reference)
//
#include <hip/hip_runtime.h>

// MoEConnectionProcessor — MI355X/gfx950 — Round 5: exact-f32 oracle, f32 OUTPUT.
// Established: inputs f32, cat int32. This round tests: output f32 (per reference).
// One kernel, no workspace, no MFMA. 1 wave = 4 cells, lane = feature.
// K-broadcast via v_readlane; weights coalesced from global (L2-resident).

#define NCELL 19683
#define KNB 26
#define CPW 4   // cells per wave
#define WPB 4   // waves per block
#define NBLK 1231  // 1231 * 16 = 19696 >= 19683

__device__ __forceinline__ float rlane(float v, int l) {
  union { float f; int i; } a; a.f = v;
  int r = __builtin_amdgcn_readlane(a.i, l);
  union { int i; float f; } b; b.i = r; return b.f;
}

// acc[c] += sum_{k=0..127} in[k] * W[k*stride + col], in[k] lane-distributed:
// k<64 from inlo[c] (lane k), k>=64 from inhi[c] (lane k-64).
__device__ __forceinline__ void gemm_col(const float* __restrict__ W, int stride, int col,
                                         const float inlo[CPW], const float inhi[CPW],
                                         float acc[CPW]) {
#pragma unroll 8
  for (int kk = 0; kk < 64; kk++) {
    float w = W[kk * stride + col];
#pragma unroll
    for (int c = 0; c < CPW; c++) acc[c] += rlane(inlo[c], kk) * w;
  }
#pragma unroll 8
  for (int kk = 0; kk < 64; kk++) {
    float w = W[(64 + kk) * stride + col];
#pragma unroll
    for (int c = 0; c < CPW; c++) acc[c] += rlane(inhi[c], kk) * w;
  }
}

__global__ __launch_bounds__(256) void k_moe(
    const float* __restrict__ cur, const float* __restrict__ nb, const int* __restrict__ cat,
    const float* __restrict__ Wl, const float* __restrict__ bl,
    const float* __restrict__ Wf1, const float* __restrict__ bf1,
    const float* __restrict__ Wf2, const float* __restrict__ bf2,
    const float* __restrict__ Wc1, const float* __restrict__ bc1,
    const float* __restrict__ Wc2, const float* __restrict__ bc2,
    const float* __restrict__ Wg1, const float* __restrict__ bg1,
    const float* __restrict__ Wg2, const float* __restrict__ bg2,
    float* __restrict__ outp) {
  int lane = threadIdx.x & 63, wv = threadIdx.x >> 6;
  int cell0 = (blockIdx.x * WPB + wv) * CPW;

  float vbl = bl[lane];
  float vbf1l = bf1[lane], vbf1h = bf1[64 + lane], vbf2 = bf2[lane];
  float vbc1l = bc1[lane], vbc1h = bc1[64 + lane], vbc2 = bc2[lane];
  float vbg1 = bg1[lane & 31];
  float wg2v[3], bg2v[3];
#pragma unroll
  for (int t = 0; t < 3; t++) {
    bg2v[t] = bg2[t];
    wg2v[t] = (lane < 32) ? Wg2[lane * 3 + t] : 0.0f;
  }

  // ---- aggregation (exact f32) ----
  float curv[CPW], ml[CPW], mf[CPW], md[CPW], av[CPW];
  float fl_l[CPW], fl_f[CPW], fl_d[CPW];
#pragma unroll
  for (int c = 0; c < CPW; c++) {
    int cell = min(cell0 + c, NCELL - 1);
    curv[c] = cur[(size_t)cell * 64 + lane];
    int catv = (lane < KNB) ? cat[(size_t)cell * KNB + lane] : -1;
    float cl = (float)__popcll(__ballot(catv == 0));
    float cf = (float)__popcll(__ballot(catv == 1));
    float cd = (float)__popcll(__ballot(catv == 2));
    float sl = 0.f, sf = 0.f, sd = 0.f, sa = 0.f;
    const float* nbc = nb + (size_t)cell * (KNB * 64) + lane;
#pragma unroll
    for (int k = 0; k < KNB; k++) {
      float v = nbc[k * 64];
      int ck = __builtin_amdgcn_readlane(catv, k);
      sa += v;
      sl += (ck == 0) ? v : 0.0f;
      sf += (ck == 1) ? v : 0.0f;
      sd += (ck == 2) ? v : 0.0f;
    }
    ml[c] = sl / fmaxf(cl, 1.0f);
    mf[c] = sf / fmaxf(cf, 1.0f);
    md[c] = sd / fmaxf(cd, 1.0f);
    av[c] = sa * (1.0f / 26.0f);
    fl_l[c] = (cl > 0.f) ? 1.f : 0.f;
    fl_f[c] = (cf > 0.f) ? 1.f : 0.f;
    fl_d[c] = (cd > 0.f) ? 1.f : 0.f;
  }

  // ---- local expert ----
  float out_l[CPW];
  {
    float acc[CPW] = {0.f, 0.f, 0.f, 0.f};
    gemm_col(Wl, 64, lane, curv, ml, acc);
#pragma unroll
    for (int c = 0; c < CPW; c++) out_l[c] = tanhf(acc[c] + vbl);
  }

  // ---- functional expert ----
  float out_f[CPW];
  {
    float alo[CPW] = {0.f, 0.f, 0.f, 0.f}, ahi[CPW] = {0.f, 0.f, 0.f, 0.f};
    gemm_col(Wf1, 128, lane, curv, mf, alo);
    gemm_col(Wf1, 128, 64 + lane, curv, mf, ahi);
    float hlo[CPW], hhi[CPW];
#pragma unroll
    for (int c = 0; c < CPW; c++) {
      hlo[c] = tanhf(alo[c] + vbf1l);
      hhi[c] = tanhf(ahi[c] + vbf1h);
    }
    float acc[CPW] = {0.f, 0.f, 0.f, 0.f};
    gemm_col(Wf2, 64, lane, hlo, hhi, acc);
#pragma unroll
    for (int c = 0; c < CPW; c++) out_f[c] = tanhf(acc[c] + vbf2);
  }

  // ---- gating ----
  float w0[CPW], w1[CPW], w2[CPW];
  {
    float accg[CPW] = {0.f, 0.f, 0.f, 0.f};
    gemm_col(Wg1, 32, lane & 31, curv, av, accg);
#pragma unroll
    for (int c = 0; c < CPW; c++) {
      float gh = (lane < 32) ? tanhf(accg[c] + vbg1) : 0.0f;
      float p0 = gh * wg2v[0], p1 = gh * wg2v[1], p2 = gh * wg2v[2];
#pragma unroll
      for (int off = 1; off < 64; off <<= 1) {
        p0 += __shfl_xor(p0, off);
        p1 += __shfl_xor(p1, off);
        p2 += __shfl_xor(p2, off);
      }
      float g0 = p0 + bg2v[0], g1v = p1 + bg2v[1], g2v = p2 + bg2v[2];
      float mx = fmaxf(g0, fmaxf(g1v, g2v));
      float e0 = expf(g0 - mx), e1 = expf(g1v - mx), e2 = expf(g2v - mx);
      float rs = 1.0f / (e0 + e1 + e2);
      w0[c] = e0 * rs; w1[c] = e1 * rs; w2[c] = e2 * rs;
    }
  }

  // ---- distant expert (CNF, 3 Euler steps) ----
  float x[CPW];
#pragma unroll
  for (int c = 0; c < CPW; c++) x[c] = curv[c];
  for (int step = 0; step < 3; step++) {
    float alo[CPW] = {0.f, 0.f, 0.f, 0.f}, ahi[CPW] = {0.f, 0.f, 0.f, 0.f};
    gemm_col(Wc1, 128, lane, x, md, alo);
    gemm_col(Wc1, 128, 64 + lane, x, md, ahi);
    float vlo[CPW], vhi[CPW];
#pragma unroll
    for (int c = 0; c < CPW; c++) {
      vlo[c] = tanhf(alo[c] + vbc1l);
      vhi[c] = tanhf(ahi[c] + vbc1h);
    }
    float acc[CPW] = {0.f, 0.f, 0.f, 0.f};
    gemm_col(Wc2, 64, lane, vlo, vhi, acc);
#pragma unroll
    for (int c = 0; c < CPW; c++) x[c] += (1.0f / 3.0f) * tanhf(acc[c] + vbc2);
  }

  // ---- combine + f32 stores ----
#pragma unroll
  for (int c = 0; c < CPW; c++) {
    int cell = cell0 + c;
    float comb = w0[c] * fl_l[c] * out_l[c] + w1[c] * fl_f[c] * out_f[c] +
                 w2[c] * fl_d[c] * x[c];
    if (cell < NCELL) {
      outp[(size_t)cell * 64 + lane] = comb;
      if (lane < 3) {
        float wsel = (lane == 0) ? w0[c] : (lane == 1) ? w1[c] : w2[c];
        outp[(size_t)NCELL * 64 + cell * 3 + lane] = wsel;
      }
    }
  }
}

extern "C" void kernel_launch(void* const* d_in, const int* in_sizes, int n_in,
                              void* d_out, int out_size, void* d_ws, size_t ws_size,
                              hipStream_t stream) {
  const float* cur = (const float*)d_in[0];
  const float* nb  = (const float*)d_in[1];
  const int* cat   = (const int*)d_in[2];
  const float* Wl  = (const float*)d_in[3];
  const float* bl  = (const float*)d_in[4];
  const float* Wf1 = (const float*)d_in[5];
  const float* bf1 = (const float*)d_in[6];
  const float* Wf2 = (const float*)d_in[7];
  const float* bf2 = (const float*)d_in[8];
  const float* Wc1 = (const float*)d_in[9];
  const float* bc1 = (const float*)d_in[10];
  const float* Wc2 = (const float*)d_in[11];
  const float* bc2 = (const float*)d_in[12];
  const float* Wg1 = (const float*)d_in[13];
  const float* bg1 = (const float*)d_in[14];
  const float* Wg2 = (const float*)d_in[15];
  const float* bg2 = (const float*)d_in[16];
  float* outp = (float*)d_out;

  k_moe<<<NBLK, 256, 0, stream>>>(cur, nb, cat, Wl, bl, Wf1, bf1, Wf2, bf2,
                                  Wc1, bc1, Wc2, bc2, Wg1, bg1, Wg2, bg2, outp);
}

// Round 6
// 303.086 us; speedup vs baseline: 1.5439x; 1.5439x over previous
//
#include <hip/hip_runtime.h>

// MoEConnectionProcessor — MI355X/gfx950 — Round 6: MFMA build.
// PROVEN: inputs f32, cat int32, output f32 (combined[N,64] ++ w[N,3]).
// MFMA fragment layouts validated empirically (r3 values == r4 oracle values).
// k_prep: masked means/activity/flags (bf16 in ws) + weight repack (f32->bf16 B-frags)
//         + cur f32->bf16 copy.
// k_mlp : per-wave 16-cell group: MFMA expert MLPs + gating + combine, f32 stores.

#define NCELL 19683
#define KNB 26
#define NGROUP 1231            // ceil(NCELL/16)
#define AGG_BLOCKS 2461        // 8 cells per 256-thr block (2 per wave)
#define RP_BLOCKS 30           // 120 frags / 4 waves
#define CUR_BLOCKS 616         // ceil(NCELL*8 / 256) uint4-granular cur copy

typedef short bf16x8 __attribute__((ext_vector_type(8)));
typedef float f32x4 __attribute__((ext_vector_type(4)));

// workspace layout (bytes)
#define MEANB (NCELL * 64 * 2)
#define OFF_ML 0
#define OFF_MF (1 * MEANB)
#define OFF_MD (2 * MEANB)
#define OFF_ACT (3 * MEANB)
#define OFF_FLAGS (4 * MEANB)             // NCELL * float4
#define OFF_RP (OFF_FLAGS + NCELL * 16)   // 120 frags * 1024B
#define OFF_CUR (OFF_RP + 120 * 1024)     // NCELL*64 bf16

// fragment bases (units of 1KB frags), frag index within matrix = nt*4 + kt
#define FB_L 0
#define FB_F1 16
#define FB_F2 48
#define FB_C1 64
#define FB_C2 96
#define FB_G1 112

__device__ __forceinline__ unsigned short f2b(float f) {
  unsigned u; __builtin_memcpy(&u, &f, 4);
  u += 0x7FFFu + ((u >> 16) & 1u);
  return (unsigned short)(u >> 16);
}

// ---------------- kernel 1: aggregation + weight repack + cur copy ----------------
__global__ __launch_bounds__(256) void k_prep(
    const float* __restrict__ nbp, const int* __restrict__ catp,
    const float* __restrict__ Wl, const float* __restrict__ Wf1,
    const float* __restrict__ Wf2, const float* __restrict__ Wc1,
    const float* __restrict__ Wc2, const float* __restrict__ Wg1,
    const float* __restrict__ curp, char* __restrict__ ws) {
  int bid = blockIdx.x;
  int tid = threadIdx.x;
  int lane = tid & 63;
  int wid = tid >> 6;

  if (bid < AGG_BLOCKS) {
    int half = lane >> 5;
    int l31 = lane & 31;
    int cell = bid * 8 + wid * 2 + half;
    int cc = min(cell, NCELL - 1);
    int myc = (l31 < KNB) ? catp[cc * KNB + l31] : -1;
    unsigned long long bl0 = __ballot(myc == 0);
    unsigned long long bl1 = __ballot(myc == 1);
    unsigned long long bl2 = __ballot(myc == 2);
    unsigned m0 = (unsigned)(bl0 >> (half * 32));
    unsigned m1 = (unsigned)(bl1 >> (half * 32));
    unsigned m2 = (unsigned)(bl2 >> (half * 32));
    float cl = (float)__popc(m0), cf = (float)__popc(m1), cd = (float)__popc(m2);

    const float* nbf = nbp + (size_t)cc * (KNB * 64) + l31 * 2;
    float sl0 = 0, sl1 = 0, sf0 = 0, sf1 = 0, sd0 = 0, sd1 = 0, sa0 = 0, sa1 = 0;
#pragma unroll
    for (int k = 0; k < KNB; k++) {
      float2 vf = *(const float2*)(nbf + k * 64);
      float v0 = vf.x, v1 = vf.y;
      int c = __shfl(myc, half * 32 + k);
      sa0 += v0; sa1 += v1;
      sl0 += (c == 0) ? v0 : 0.0f; sl1 += (c == 0) ? v1 : 0.0f;
      sf0 += (c == 1) ? v0 : 0.0f; sf1 += (c == 1) ? v1 : 0.0f;
      sd0 += (c == 2) ? v0 : 0.0f; sd1 += (c == 2) ? v1 : 0.0f;
    }
    float rl = 1.0f / fmaxf(cl, 1.0f);
    float rf = 1.0f / fmaxf(cf, 1.0f);
    float rd = 1.0f / fmaxf(cd, 1.0f);
    const float r26 = 1.0f / 26.0f;
    if (cell < NCELL) {
      int off = cell * 128 + l31 * 4;
      *(unsigned*)(ws + OFF_ML + off) = (unsigned)f2b(sl0 * rl) | ((unsigned)f2b(sl1 * rl) << 16);
      *(unsigned*)(ws + OFF_MF + off) = (unsigned)f2b(sf0 * rf) | ((unsigned)f2b(sf1 * rf) << 16);
      *(unsigned*)(ws + OFF_MD + off) = (unsigned)f2b(sd0 * rd) | ((unsigned)f2b(sd1 * rd) << 16);
      *(unsigned*)(ws + OFF_ACT + off) = (unsigned)f2b(sa0 * r26) | ((unsigned)f2b(sa1 * r26) << 16);
      if (l31 == 0) {
        float4 fl;
        fl.x = (cl > 0.0f) ? 1.0f : 0.0f;
        fl.y = (cf > 0.0f) ? 1.0f : 0.0f;
        fl.z = (cd > 0.0f) ? 1.0f : 0.0f;
        fl.w = 0.0f;
        *(float4*)(ws + OFF_FLAGS + cell * 16) = fl;
      }
    }
  } else if (bid < AGG_BLOCKS + RP_BLOCKS) {
    // repack: one frag/wave. B[k][n]: n = lane&15, k = kt*32 + (lane>>4)*8 + j
    int frag = (bid - AGG_BLOCKS) * 4 + wid;
    if (frag >= 120) return;
    const float* src; int Nd, lf;
    if (frag < 16)       { src = Wl;  Nd = 64;  lf = frag; }
    else if (frag < 48)  { src = Wf1; Nd = 128; lf = frag - 16; }
    else if (frag < 64)  { src = Wf2; Nd = 64;  lf = frag - 48; }
    else if (frag < 96)  { src = Wc1; Nd = 128; lf = frag - 64; }
    else if (frag < 112) { src = Wc2; Nd = 64;  lf = frag - 96; }
    else                 { src = Wg1; Nd = 32;  lf = frag - 112; }
    int nt = lf >> 2, kt = lf & 3;
    int n = nt * 16 + (lane & 15);
    int k0 = kt * 32 + (lane >> 4) * 8;
    unsigned short o[8] __attribute__((aligned(16)));
#pragma unroll
    for (int j = 0; j < 8; j++) o[j] = f2b(src[(k0 + j) * Nd + n]);
    *(uint4*)(ws + OFF_RP + ((size_t)frag * 64 + lane) * 16) = *(const uint4*)o;
  } else {
    // cur f32 -> bf16 copy (uint4 = 8 bf16 per thread)
    int idx = (bid - AGG_BLOCKS - RP_BLOCKS) * 256 + tid;
    if (idx >= NCELL * 8) return;
    float4 a = ((const float4*)curp)[idx * 2];
    float4 b = ((const float4*)curp)[idx * 2 + 1];
    uint4 o;
    o.x = (unsigned)f2b(a.x) | ((unsigned)f2b(a.y) << 16);
    o.y = (unsigned)f2b(a.z) | ((unsigned)f2b(a.w) << 16);
    o.z = (unsigned)f2b(b.x) | ((unsigned)f2b(b.y) << 16);
    o.w = (unsigned)f2b(b.z) | ((unsigned)f2b(b.w) << 16);
    ((uint4*)(ws + OFF_CUR))[idx] = o;
  }
}

// ---------------- kernel 2 helpers (LDS in uint4 units, 16B-aligned) ----------------
__device__ __forceinline__ void stage64(const uint4* __restrict__ src, int g, uint4* dst, int lane) {
#pragma unroll
  for (int i = 0; i < 2; i++) {
    int idx = min(g * 128 + i * 64 + lane, NCELL * 8 - 1);
    uint4 v = src[idx];
    int local = i * 64 + lane;
    int cell = local >> 3, c = local & 7;
    dst[cell * 8 + (c ^ (cell & 7))] = v;
  }
}
__device__ __forceinline__ void afrags2(const uint4* lo, const uint4* hi, int m, int q, bf16x8* a) {
#pragma unroll
  for (int kt = 0; kt < 4; kt++) {
    const uint4* b = (kt < 2) ? lo : hi;
    int ch = ((kt & 1) * 4 + q) ^ (m & 7);
    a[kt] = *(const bf16x8*)&b[m * 8 + ch];
  }
}
__device__ __forceinline__ void afragsS(const uint4* sb, int m, int q, bf16x8* a) {
#pragma unroll
  for (int kt = 0; kt < 4; kt++) {
    int ch = (kt * 4 + q) ^ m;
    a[kt] = *(const bf16x8*)&sb[m * 16 + ch];
  }
}
template <int NT>
__device__ __forceinline__ void gemmN(const bf16x8* __restrict__ wf, int fb, const bf16x8* a,
                                      int lane, f32x4* out) {
#pragma unroll
  for (int nt = 0; nt < NT; nt++) {
    f32x4 acc = {0.f, 0.f, 0.f, 0.f};
#pragma unroll
    for (int kt = 0; kt < 4; kt++) {
      bf16x8 b = wf[(fb + nt * 4 + kt) * 64 + lane];
      acc = __builtin_amdgcn_mfma_f32_16x16x32_bf16(a[kt], b, acc, 0, 0, 0);
    }
    out[nt] = acc;
  }
}
__device__ __forceinline__ void store_sb(uint4* sb, int cell, int feat, float v) {
  ((unsigned short*)&sb[cell * 16 + ((feat >> 3) ^ cell)])[feat & 7] = f2b(v);
}
__device__ __forceinline__ void store_xb(uint4* xb, int cell, int feat, float v) {
  ((unsigned short*)&xb[cell * 8 + ((feat >> 3) ^ (cell & 7))])[feat & 7] = f2b(v);
}

// ---------------- kernel 2: experts + gating + combine ----------------
__global__ __launch_bounds__(256) void k_mlp(
    const float* __restrict__ curp,
    const float* __restrict__ bl_, const float* __restrict__ bf1_,
    const float* __restrict__ bf2_, const float* __restrict__ bc1_,
    const float* __restrict__ bc2_, const float* __restrict__ bg1_,
    const float* __restrict__ Wg2, const float* __restrict__ bg2_,
    const char* __restrict__ ws, float* __restrict__ outp) {
  __shared__ uint4 smem[4 * 640];
  int tid = threadIdx.x, lane = tid & 63, wv = tid >> 6;
  int g = blockIdx.x * 4 + wv;
  if (g >= NGROUP) return;  // wave-uniform; per-wave LDS only, no block sync
  uint4* wbase = smem + wv * 640;
  uint4* curb = wbase;
  uint4* mb = wbase + 128;
  uint4* xb = wbase + 256;
  uint4* sb = wbase + 384;

  const unsigned short* curh = (const unsigned short*)(ws + OFF_CUR);
  int m = lane & 15, q = lane >> 4;
  const bf16x8* wf = (const bf16x8*)(ws + OFF_RP);
  bf16x8 a[4];

  // ---- local expert ----
  stage64((const uint4*)curh, g, curb, lane);
  stage64((const uint4*)(ws + OFF_ML), g, mb, lane);
  afrags2(curb, mb, m, q, a);
  f32x4 ol[4];
  gemmN<4>(wf, FB_L, a, lane, ol);
#pragma unroll
  for (int nt = 0; nt < 4; nt++) {
    float bb = bl_[nt * 16 + m];
#pragma unroll
    for (int r = 0; r < 4; r++) ol[nt][r] = tanhf(ol[nt][r] + bb);
  }

  // ---- functional expert ----
  stage64((const uint4*)(ws + OFF_MF), g, mb, lane);
  afrags2(curb, mb, m, q, a);
  f32x4 h8[8];
  gemmN<8>(wf, FB_F1, a, lane, h8);
#pragma unroll
  for (int nt = 0; nt < 8; nt++) {
    float bb = bf1_[nt * 16 + m];
#pragma unroll
    for (int r = 0; r < 4; r++) store_sb(sb, q * 4 + r, nt * 16 + m, tanhf(h8[nt][r] + bb));
  }
  afragsS(sb, m, q, a);
  f32x4 of[4];
  gemmN<4>(wf, FB_F2, a, lane, of);
#pragma unroll
  for (int nt = 0; nt < 4; nt++) {
    float bb = bf2_[nt * 16 + m];
#pragma unroll
    for (int r = 0; r < 4; r++) of[nt][r] = tanhf(of[nt][r] + bb);
  }

  // ---- gating ----
  stage64((const uint4*)(ws + OFF_ACT), g, mb, lane);
  afrags2(curb, mb, m, q, a);
  f32x4 gh[2];
  gemmN<2>(wf, FB_G1, a, lane, gh);
#pragma unroll
  for (int nt = 0; nt < 2; nt++) {
    float bb = bg1_[nt * 16 + m];
#pragma unroll
    for (int r = 0; r < 4; r++) gh[nt][r] = tanhf(gh[nt][r] + bb);
  }
  float w2v[2][3];
#pragma unroll
  for (int nt = 0; nt < 2; nt++)
#pragma unroll
    for (int t = 0; t < 3; t++) w2v[nt][t] = Wg2[(nt * 16 + m) * 3 + t];
  float bg2v[3];
#pragma unroll
  for (int t = 0; t < 3; t++) bg2v[t] = bg2_[t];
  float w0[4], w1[4], w2[4];
#pragma unroll
  for (int r = 0; r < 4; r++) {
    float gv[3];
#pragma unroll
    for (int t = 0; t < 3; t++) {
      float p = gh[0][r] * w2v[0][t] + gh[1][r] * w2v[1][t];
      p += __shfl_xor(p, 1); p += __shfl_xor(p, 2); p += __shfl_xor(p, 4); p += __shfl_xor(p, 8);
      gv[t] = p + bg2v[t];
    }
    float mx = fmaxf(gv[0], fmaxf(gv[1], gv[2]));
    float e0 = expf(gv[0] - mx), e1 = expf(gv[1] - mx), e2 = expf(gv[2] - mx);
    float rs = 1.0f / (e0 + e1 + e2);
    w0[r] = e0 * rs; w1[r] = e1 * rs; w2[r] = e2 * rs;
    int cell = g * 16 + q * 4 + r;
    if (cell < NCELL && m < 3) {
      float wsel = (m == 0) ? w0[r] : (m == 1) ? w1[r] : w2[r];
      outp[(size_t)NCELL * 64 + cell * 3 + m] = wsel;
    }
  }

  // ---- distant expert (CNF, 3 Euler steps; x f32 in regs, init from f32 cur) ----
  stage64((const uint4*)(ws + OFF_MD), g, mb, lane);
  float xr[4][4];
#pragma unroll
  for (int nt = 0; nt < 4; nt++)
#pragma unroll
    for (int r = 0; r < 4; r++) {
      int cell = min(g * 16 + q * 4 + r, NCELL - 1);
      xr[nt][r] = curp[(size_t)cell * 64 + nt * 16 + m];
    }
  for (int step = 0; step < 3; step++) {
#pragma unroll
    for (int nt = 0; nt < 4; nt++)
#pragma unroll
      for (int r = 0; r < 4; r++) store_xb(xb, q * 4 + r, nt * 16 + m, xr[nt][r]);
    afrags2(xb, mb, m, q, a);
    f32x4 v8[8];
    gemmN<8>(wf, FB_C1, a, lane, v8);
#pragma unroll
    for (int nt = 0; nt < 8; nt++) {
      float bb = bc1_[nt * 16 + m];
#pragma unroll
      for (int r = 0; r < 4; r++) store_sb(sb, q * 4 + r, nt * 16 + m, tanhf(v8[nt][r] + bb));
    }
    afragsS(sb, m, q, a);
    f32x4 dx[4];
    gemmN<4>(wf, FB_C2, a, lane, dx);
#pragma unroll
    for (int nt = 0; nt < 4; nt++) {
      float bb = bc2_[nt * 16 + m];
#pragma unroll
      for (int r = 0; r < 4; r++) xr[nt][r] += (1.0f / 3.0f) * tanhf(dx[nt][r] + bb);
    }
  }

  // ---- combine (f32 stores) ----
  float4 flg[4];
  const float4* flp = (const float4*)(ws + OFF_FLAGS);
#pragma unroll
  for (int r = 0; r < 4; r++) flg[r] = flp[min(g * 16 + q * 4 + r, NCELL - 1)];
#pragma unroll
  for (int nt = 0; nt < 4; nt++)
#pragma unroll
    for (int r = 0; r < 4; r++) {
      float res = w0[r] * flg[r].x * ol[nt][r] + w1[r] * flg[r].y * of[nt][r] +
                  w2[r] * flg[r].z * xr[nt][r];
      int cell = g * 16 + q * 4 + r;
      if (cell < NCELL) outp[(size_t)cell * 64 + nt * 16 + m] = res;
    }
}

extern "C" void kernel_launch(void* const* d_in, const int* in_sizes, int n_in,
                              void* d_out, int out_size, void* d_ws, size_t ws_size,
                              hipStream_t stream) {
  const float* cur = (const float*)d_in[0];
  const float* nb  = (const float*)d_in[1];
  const int* cat   = (const int*)d_in[2];
  const float* Wl  = (const float*)d_in[3];
  const float* bl  = (const float*)d_in[4];
  const float* Wf1 = (const float*)d_in[5];
  const float* bf1 = (const float*)d_in[6];
  const float* Wf2 = (const float*)d_in[7];
  const float* bf2 = (const float*)d_in[8];
  const float* Wc1 = (const float*)d_in[9];
  const float* bc1 = (const float*)d_in[10];
  const float* Wc2 = (const float*)d_in[11];
  const float* bc2 = (const float*)d_in[12];
  const float* Wg1 = (const float*)d_in[13];
  const float* bg1 = (const float*)d_in[14];
  const float* Wg2 = (const float*)d_in[15];
  const float* bg2 = (const float*)d_in[16];
  char* ws = (char*)d_ws;
  float* outp = (float*)d_out;

  k_prep<<<AGG_BLOCKS + RP_BLOCKS + CUR_BLOCKS, 256, 0, stream>>>(
      nb, cat, Wl, Wf1, Wf2, Wc1, Wc2, Wg1, cur, ws);
  k_mlp<<<(NGROUP + 3) / 4, 256, 0, stream>>>(cur, bl, bf1, bf2, bc1, bc2, bg1, Wg2, bg2,
                                              (const char*)ws, outp);
}

// Round 7
// 248.701 us; speedup vs baseline: 1.8816x; 1.2187x over previous
//
#include <hip/hip_runtime.h>

// MoEConnectionProcessor — MI355X/gfx950 — Round 7: fused, expert-parallel.
// PROVEN: inputs f32, cat int32, output f32 (combined[N,64] ++ w[N,3]).
// k_repack: 120 MFMA B-fragments (f32->bf16) into ws.
// k_main : 1 block = 16 cells. Phase A: all 4 waves aggregate (bitmask, float4)
//          + stage cur -> LDS bf16. Phase B: w0 local+gating, w1 functional,
//          w2/w3 CNF (split by N-cols, 2 barriers/step). Cooperative combine.

#define NCELL 19683
#define KNB 26
#define NGRP 1231  // ceil(NCELL/16)

typedef short bf16x8 __attribute__((ext_vector_type(8)));
typedef float f32x4 __attribute__((ext_vector_type(4)));

// fragment bases (1KB frags), frag index in matrix = nt*4 + kt
#define FB_L 0
#define FB_F1 16
#define FB_F2 48
#define FB_C1 64
#define FB_C2 96
#define FB_G1 112

__device__ __forceinline__ unsigned short f2b(float f) {
  unsigned u; __builtin_memcpy(&u, &f, 4);
  u += 0x7FFFu + ((u >> 16) & 1u);
  return (unsigned short)(u >> 16);
}
__device__ __forceinline__ unsigned pack2(float x, float y) {
  return (unsigned)f2b(x) | ((unsigned)f2b(y) << 16);
}
__device__ __forceinline__ float tanh_fast(float x) {
  float e = __expf(2.0f * x);
  return 1.0f - 2.0f * __builtin_amdgcn_rcpf(e + 1.0f);  // exact at +/-inf
}

// ---------------- weight repack (120 frags, one per wave) ----------------
__global__ __launch_bounds__(256) void k_repack(
    const float* __restrict__ Wl, const float* __restrict__ Wf1,
    const float* __restrict__ Wf2, const float* __restrict__ Wc1,
    const float* __restrict__ Wc2, const float* __restrict__ Wg1,
    char* __restrict__ ws) {
  int frag = blockIdx.x * 4 + (threadIdx.x >> 6);
  int lane = threadIdx.x & 63;
  if (frag >= 120) return;
  const float* src; int Nd, lf;
  if (frag < 16)       { src = Wl;  Nd = 64;  lf = frag; }
  else if (frag < 48)  { src = Wf1; Nd = 128; lf = frag - 16; }
  else if (frag < 64)  { src = Wf2; Nd = 64;  lf = frag - 48; }
  else if (frag < 96)  { src = Wc1; Nd = 128; lf = frag - 64; }
  else if (frag < 112) { src = Wc2; Nd = 64;  lf = frag - 96; }
  else                 { src = Wg1; Nd = 32;  lf = frag - 112; }
  int nt = lf >> 2, kt = lf & 3;
  int n = nt * 16 + (lane & 15);
  int k0 = kt * 32 + (lane >> 4) * 8;
  unsigned short o[8] __attribute__((aligned(16)));
#pragma unroll
  for (int j = 0; j < 8; j++) o[j] = f2b(src[(k0 + j) * Nd + n]);
  *(uint4*)(ws + ((size_t)frag * 64 + lane) * 16) = *(const uint4*)o;
}

// ---------------- LDS fragment helpers (validated r3≡r4) ----------------
__device__ __forceinline__ void afrags2(const uint4* lo, const uint4* hi, int m, int q, bf16x8* a) {
#pragma unroll
  for (int kt = 0; kt < 4; kt++) {
    const uint4* b = (kt < 2) ? lo : hi;
    int ch = ((kt & 1) * 4 + q) ^ (m & 7);
    a[kt] = *(const bf16x8*)&b[m * 8 + ch];
  }
}
__device__ __forceinline__ void afragsS(const uint4* sb, int m, int q, bf16x8* a) {
#pragma unroll
  for (int kt = 0; kt < 4; kt++) {
    int ch = (kt * 4 + q) ^ m;
    a[kt] = *(const bf16x8*)&sb[m * 16 + ch];
  }
}
template <int NT>
__device__ __forceinline__ void gemmN(const bf16x8* __restrict__ wf, int fb, const bf16x8* a,
                                      int lane, f32x4* out) {
#pragma unroll
  for (int nt = 0; nt < NT; nt++) {
    f32x4 acc = {0.f, 0.f, 0.f, 0.f};
#pragma unroll
    for (int kt = 0; kt < 4; kt++) {
      bf16x8 b = wf[(fb + nt * 4 + kt) * 64 + lane];
      acc = __builtin_amdgcn_mfma_f32_16x16x32_bf16(a[kt], b, acc, 0, 0, 0);
    }
    out[nt] = acc;
  }
}
__device__ __forceinline__ void store_sb(uint4* sb, int cell, int feat, float v) {
  ((unsigned short*)&sb[cell * 16 + ((feat >> 3) ^ cell)])[feat & 7] = f2b(v);
}
__device__ __forceinline__ void store_xb(uint4* xb, int cell, int feat, float v) {
  ((unsigned short*)&xb[cell * 8 + ((feat >> 3) ^ (cell & 7))])[feat & 7] = f2b(v);
}

// ---------------- fused main kernel ----------------
__global__ __launch_bounds__(256, 4) void k_main(
    const float* __restrict__ curp, const float* __restrict__ nbp, const int* __restrict__ catp,
    const float* __restrict__ bl_, const float* __restrict__ bf1_, const float* __restrict__ bf2_,
    const float* __restrict__ bc1_, const float* __restrict__ bc2_, const float* __restrict__ bg1_,
    const float* __restrict__ Wg2, const float* __restrict__ bg2_,
    const char* __restrict__ ws, float* __restrict__ outp) {
  __shared__ uint4 smem[2080];  // 33280 B
  uint4* curb = smem;           // 128: 16 cells x 64 bf16, swizzled
  uint4* mlb  = smem + 128;     // 128
  uint4* mfb  = smem + 256;     // 128
  uint4* mdb  = smem + 384;     // 128
  uint4* actb = smem + 512;     // 128
  uint4* xb   = smem + 640;     // 128
  uint4* sbF  = smem + 768;     // 256: 16 x 128 bf16
  uint4* sbC  = smem + 1024;    // 256
  float* outL = (float*)(smem + 1280);  // 16 x 64 f32
  float* outF = (float*)(smem + 1536);
  float* outD = (float*)(smem + 1792);
  float4* flagsb = (float4*)(smem + 2048);  // 16
  float4* wvalsb = (float4*)(smem + 2064);  // 16

  int tid = threadIdx.x, lane = tid & 63, wv = tid >> 6;
  int g = blockIdx.x;

  // ---- phase A: aggregation (each wave: 4 cells; lane: cell=lane>>4, 4 feats) ----
  {
    int cq = lane >> 4, fq = lane & 15;
    int cellLoc = wv * 4 + cq;
    int cell = min(g * 16 + cellLoc, NCELL - 1);
    int c0 = catp[cell * KNB + fq];
    int c1 = (fq < KNB - 16) ? catp[cell * KNB + 16 + fq] : -1;
    unsigned long long B0a = __ballot(c0 == 0), B1a = __ballot(c0 == 1), B2a = __ballot(c0 == 2);
    unsigned long long B0b = __ballot(c1 == 0), B1b = __ballot(c1 == 1), B2b = __ballot(c1 == 2);
    int sh = cq * 16;
    unsigned m0 = (unsigned)((B0a >> sh) & 0xFFFFull) | ((unsigned)((B0b >> sh) & 0x3FFull) << 16);
    unsigned m1 = (unsigned)((B1a >> sh) & 0xFFFFull) | ((unsigned)((B1b >> sh) & 0x3FFull) << 16);
    unsigned m2 = (unsigned)((B2a >> sh) & 0xFFFFull) | ((unsigned)((B2b >> sh) & 0x3FFull) << 16);
    float cl = (float)__popc(m0), cf = (float)__popc(m1), cd = (float)__popc(m2);
    float sl[4] = {0, 0, 0, 0}, sf[4] = {0, 0, 0, 0}, sd[4] = {0, 0, 0, 0}, sa[4] = {0, 0, 0, 0};
    const float* nbc = nbp + (size_t)cell * (KNB * 64) + fq * 4;
#pragma unroll
    for (int k = 0; k < KNB; k++) {
      float4 v = *(const float4*)(nbc + k * 64);
      float b0 = (float)((m0 >> k) & 1u);
      float b1 = (float)((m1 >> k) & 1u);
      float b2 = (float)((m2 >> k) & 1u);
      sa[0] += v.x; sa[1] += v.y; sa[2] += v.z; sa[3] += v.w;
      sl[0] += b0 * v.x; sl[1] += b0 * v.y; sl[2] += b0 * v.z; sl[3] += b0 * v.w;
      sf[0] += b1 * v.x; sf[1] += b1 * v.y; sf[2] += b1 * v.z; sf[3] += b1 * v.w;
      sd[0] += b2 * v.x; sd[1] += b2 * v.y; sd[2] += b2 * v.z; sd[3] += b2 * v.w;
    }
    float rl = 1.0f / fmaxf(cl, 1.0f);
    float rf = 1.0f / fmaxf(cf, 1.0f);
    float rd = 1.0f / fmaxf(cd, 1.0f);
    const float r26 = 1.0f / 26.0f;
    int ch = (fq >> 1) ^ (cellLoc & 7);
    int sub = fq & 1;
    ((uint2*)&mlb[cellLoc * 8 + ch])[sub] =
        make_uint2(pack2(sl[0] * rl, sl[1] * rl), pack2(sl[2] * rl, sl[3] * rl));
    ((uint2*)&mfb[cellLoc * 8 + ch])[sub] =
        make_uint2(pack2(sf[0] * rf, sf[1] * rf), pack2(sf[2] * rf, sf[3] * rf));
    ((uint2*)&mdb[cellLoc * 8 + ch])[sub] =
        make_uint2(pack2(sd[0] * rd, sd[1] * rd), pack2(sd[2] * rd, sd[3] * rd));
    ((uint2*)&actb[cellLoc * 8 + ch])[sub] =
        make_uint2(pack2(sa[0] * r26, sa[1] * r26), pack2(sa[2] * r26, sa[3] * r26));
    if (fq == 0)
      flagsb[cellLoc] = make_float4(cl > 0.f ? 1.f : 0.f, cf > 0.f ? 1.f : 0.f,
                                    cd > 0.f ? 1.f : 0.f, 0.f);
  }
  // cur -> LDS bf16 (threads 0..127)
  if (tid < 128) {
    int cellLoc = tid >> 3, c = tid & 7;
    int cell = min(g * 16 + cellLoc, NCELL - 1);
    const float4* cp = (const float4*)(curp + (size_t)cell * 64) + c * 2;
    float4 A = cp[0], B = cp[1];
    uint4 o;
    o.x = pack2(A.x, A.y); o.y = pack2(A.z, A.w);
    o.z = pack2(B.x, B.y); o.w = pack2(B.z, B.w);
    curb[cellLoc * 8 + (c ^ (cellLoc & 7))] = o;
  }

  int m = lane & 15, q = lane >> 4;
  const bf16x8* wf = (const bf16x8*)ws;
  bf16x8 a4[4];
  float xr[2][4];

  // CNF x init from f32 cur (global; no LDS dependency)
  if (wv >= 2) {
    int ntb = (wv - 2) * 2;
#pragma unroll
    for (int j = 0; j < 2; j++)
#pragma unroll
      for (int r = 0; r < 4; r++) {
        int cell = min(g * 16 + q * 4 + r, NCELL - 1);
        xr[j][r] = curp[(size_t)cell * 64 + (ntb + j) * 16 + m];
      }
  }
  __syncthreads();  // (1) staging complete

  if (wv == 0) {
    // ---- local expert ----
    afrags2(curb, mlb, m, q, a4);
    f32x4 ol[4];
    gemmN<4>(wf, FB_L, a4, lane, ol);
#pragma unroll
    for (int nt = 0; nt < 4; nt++) {
      float bb = bl_[nt * 16 + m];
#pragma unroll
      for (int r = 0; r < 4; r++) outL[(q * 4 + r) * 64 + nt * 16 + m] = tanh_fast(ol[nt][r] + bb);
    }
    // ---- gating ----
    afrags2(curb, actb, m, q, a4);
    f32x4 gh[2];
    gemmN<2>(wf, FB_G1, a4, lane, gh);
#pragma unroll
    for (int nt = 0; nt < 2; nt++) {
      float bb = bg1_[nt * 16 + m];
#pragma unroll
      for (int r = 0; r < 4; r++) gh[nt][r] = tanh_fast(gh[nt][r] + bb);
    }
    float w2v[2][3];
#pragma unroll
    for (int nt = 0; nt < 2; nt++)
#pragma unroll
      for (int t = 0; t < 3; t++) w2v[nt][t] = Wg2[(nt * 16 + m) * 3 + t];
    float bg2v[3] = {bg2_[0], bg2_[1], bg2_[2]};
#pragma unroll
    for (int r = 0; r < 4; r++) {
      float gv[3];
#pragma unroll
      for (int t = 0; t < 3; t++) {
        float p = gh[0][r] * w2v[0][t] + gh[1][r] * w2v[1][t];
        p += __shfl_xor(p, 1); p += __shfl_xor(p, 2); p += __shfl_xor(p, 4); p += __shfl_xor(p, 8);
        gv[t] = p + bg2v[t];
      }
      float mx = fmaxf(gv[0], fmaxf(gv[1], gv[2]));
      float e0 = __expf(gv[0] - mx), e1 = __expf(gv[1] - mx), e2 = __expf(gv[2] - mx);
      float rs = __builtin_amdgcn_rcpf(e0 + e1 + e2);
      int cellLoc = q * 4 + r;
      int cell = g * 16 + cellLoc;
      if (m == 0) wvalsb[cellLoc] = make_float4(e0 * rs, e1 * rs, e2 * rs, 0.f);
      if (cell < NCELL && m < 3) {
        float wsel = (m == 0) ? e0 * rs : (m == 1) ? e1 * rs : e2 * rs;
        outp[(size_t)NCELL * 64 + cell * 3 + m] = wsel;
      }
    }
  } else if (wv == 1) {
    // ---- functional expert ----
    afrags2(curb, mfb, m, q, a4);
    f32x4 h8[8];
    gemmN<8>(wf, FB_F1, a4, lane, h8);
#pragma unroll
    for (int nt = 0; nt < 8; nt++) {
      float bb = bf1_[nt * 16 + m];
#pragma unroll
      for (int r = 0; r < 4; r++)
        store_sb(sbF, q * 4 + r, nt * 16 + m, tanh_fast(h8[nt][r] + bb));
    }
    afragsS(sbF, m, q, a4);
    f32x4 of4[4];
    gemmN<4>(wf, FB_F2, a4, lane, of4);
#pragma unroll
    for (int nt = 0; nt < 4; nt++) {
      float bb = bf2_[nt * 16 + m];
#pragma unroll
      for (int r = 0; r < 4; r++)
        outF[(q * 4 + r) * 64 + nt * 16 + m] = tanh_fast(of4[nt][r] + bb);
    }
  } else {
    // ---- CNF: write x init to xb (disjoint feat halves) ----
    int ntb = (wv - 2) * 2;
#pragma unroll
    for (int j = 0; j < 2; j++)
#pragma unroll
      for (int r = 0; r < 4; r++) store_xb(xb, q * 4 + r, (ntb + j) * 16 + m, xr[j][r]);
  }

  // ---- CNF steps: w2 (h cols 0..63, dx 0..31) + w3 (h 64..127, dx 32..63) ----
  for (int step = 0; step < 3; step++) {
    __syncthreads();  // (2,4,6) xb ready, sbC free
    if (wv >= 2) {
      int hb = (wv - 2) * 4;
      afrags2(xb, mdb, m, q, a4);
      f32x4 v4[4];
      gemmN<4>(wf, FB_C1 + hb * 4, a4, lane, v4);
#pragma unroll
      for (int j = 0; j < 4; j++) {
        int nt = hb + j;
        float bb = bc1_[nt * 16 + m];
#pragma unroll
        for (int r = 0; r < 4; r++)
          store_sb(sbC, q * 4 + r, nt * 16 + m, tanh_fast(v4[j][r] + bb));
      }
    }
    __syncthreads();  // (3,5,7) h ready
    if (wv >= 2) {
      int ntb = (wv - 2) * 2;
      afragsS(sbC, m, q, a4);
      f32x4 dx2[2];
      gemmN<2>(wf, FB_C2 + ntb * 4, a4, lane, dx2);
#pragma unroll
      for (int j = 0; j < 2; j++) {
        int nt = ntb + j;
        float bb = bc2_[nt * 16 + m];
#pragma unroll
        for (int r = 0; r < 4; r++) {
          xr[j][r] += (1.0f / 3.0f) * tanh_fast(dx2[j][r] + bb);
          if (step < 2) store_xb(xb, q * 4 + r, nt * 16 + m, xr[j][r]);
          else outD[(q * 4 + r) * 64 + nt * 16 + m] = xr[j][r];
        }
      }
    }
  }
  __syncthreads();  // (8) all expert outputs in LDS

  // ---- cooperative combine + coalesced float4 store ----
  {
    int cellLoc = tid >> 4, fi = tid & 15;
    float4 vl = ((const float4*)outL)[cellLoc * 16 + fi];
    float4 vf = ((const float4*)outF)[cellLoc * 16 + fi];
    float4 vd = ((const float4*)outD)[cellLoc * 16 + fi];
    float4 fl = flagsb[cellLoc];
    float4 wv4 = wvalsb[cellLoc];
    float a0 = wv4.x * fl.x, a1 = wv4.y * fl.y, a2 = wv4.z * fl.z;
    int cell = g * 16 + cellLoc;
    if (cell < NCELL) {
      float4 res;
      res.x = a0 * vl.x + a1 * vf.x + a2 * vd.x;
      res.y = a0 * vl.y + a1 * vf.y + a2 * vd.y;
      res.z = a0 * vl.z + a1 * vf.z + a2 * vd.z;
      res.w = a0 * vl.w + a1 * vf.w + a2 * vd.w;
      ((float4*)(outp + (size_t)cell * 64))[fi] = res;
    }
  }
}

extern "C" void kernel_launch(void* const* d_in, const int* in_sizes, int n_in,
                              void* d_out, int out_size, void* d_ws, size_t ws_size,
                              hipStream_t stream) {
  const float* cur = (const float*)d_in[0];
  const float* nb  = (const float*)d_in[1];
  const int* cat   = (const int*)d_in[2];
  const float* Wl  = (const float*)d_in[3];
  const float* bl  = (const float*)d_in[4];
  const float* Wf1 = (const float*)d_in[5];
  const float* bf1 = (const float*)d_in[6];
  const float* Wf2 = (const float*)d_in[7];
  const float* bf2 = (const float*)d_in[8];
  const float* Wc1 = (const float*)d_in[9];
  const float* bc1 = (const float*)d_in[10];
  const float* Wc2 = (const float*)d_in[11];
  const float* bc2 = (const float*)d_in[12];
  const float* Wg1 = (const float*)d_in[13];
  const float* bg1 = (const float*)d_in[14];
  const float* Wg2 = (const float*)d_in[15];
  const float* bg2 = (const float*)d_in[16];
  char* ws = (char*)d_ws;
  float* outp = (float*)d_out;

  k_repack<<<30, 256, 0, stream>>>(Wl, Wf1, Wf2, Wc1, Wc2, Wg1, ws);
  k_main<<<NGRP, 256, 0, stream>>>(cur, nb, cat, bl, bf1, bf2, bc1, bc2, bg1, Wg2, bg2,
                                   (const char*)ws, outp);
}